// Round 1
// baseline (7071.208 us; speedup 1.0000x reference)
//
#include <hip/hip_runtime.h>
#include <math.h>

#define Bz 64
#define Tz 12000
#define Pz 50
#define Dz 200
#define Lz 12
#define Hz 10
#define HDz 20
#define FFz 800
#define Nz 240
#define Sz 241
#define NRDz 482
#define NCz 1000
#define BS (Bz * Sz)          // 15424
#define SCALEq 0.22360679774997896f

// ---------------- patch embed: tok[b,s,d] ----------------
__global__ void patch_embed_k(const float* __restrict__ x, const float* __restrict__ cw,
                              const float* __restrict__ cb, const float* __restrict__ cls,
                              const float* __restrict__ pos, float* __restrict__ tok) {
    int bs = blockIdx.x;              // 0..BS-1
    int b = bs / Sz, s = bs % Sz;
    int d = threadIdx.x;
    __shared__ float xp[Pz];
    if (s == 0) {
        if (d < Dz) tok[(size_t)bs * Dz + d] = cls[d] + pos[d];
        return;
    }
    if (d < Pz) xp[d] = x[(size_t)b * Tz + (s - 1) * Pz + d];
    __syncthreads();
    if (d < Dz) {
        float acc = cb[d];
        const float* w = cw + d * Pz;
        #pragma unroll
        for (int p = 0; p < Pz; ++p) acc += xp[p] * w[p];
        tok[(size_t)bs * Dz + d] = acc + pos[s * Dz + d];
    }
}

// ---------------- layernorm: out = LN(in)*s+b, rows x 200 ----------------
__global__ void ln_k(const float* __restrict__ in, float* __restrict__ out,
                     const float* __restrict__ sc, const float* __restrict__ bi, int rows) {
    int wave = threadIdx.x >> 6, lane = threadIdx.x & 63;
    int row = blockIdx.x * 4 + wave;
    if (row >= rows) return;
    const float* x = in + (size_t)row * Dz;
    float v[4];
    float sum = 0.f;
    #pragma unroll
    for (int i = 0; i < 4; ++i) {
        int d = lane + 64 * i;
        v[i] = (d < Dz) ? x[d] : 0.f;
        sum += v[i];
    }
    #pragma unroll
    for (int off = 32; off; off >>= 1) sum += __shfl_xor(sum, off);
    float mean = sum * (1.f / Dz);
    float var = 0.f;
    #pragma unroll
    for (int i = 0; i < 4; ++i) {
        int d = lane + 64 * i;
        if (d < Dz) { float t = v[i] - mean; var += t * t; }
    }
    #pragma unroll
    for (int off = 32; off; off >>= 1) var += __shfl_xor(var, off);
    var *= (1.f / Dz);
    float rstd = rsqrtf(var + 1e-6f);
    float* o = out + (size_t)row * Dz;
    #pragma unroll
    for (int i = 0; i < 4; ++i) {
        int d = lane + 64 * i;
        if (d < Dz) o[d] = (v[i] - mean) * rstd * sc[d] + bi[d];
    }
}

// ---------------- generic tiled GEMM: out[M,N] = A[M,K] @ W[N,K]^T (+ epilogue) ----------------
// MODE 0: +bias      MODE 1: qkv bias (q_bias | 0 | v_bias)
// MODE 2: +bias+res  MODE 3: gelu(+bias)
template <int MODE>
__global__ void gemm_nt_k(const float* __restrict__ A, const float* __restrict__ W,
                          const float* __restrict__ bias, const float* __restrict__ bias2,
                          const float* __restrict__ res, float* __restrict__ out,
                          int M, int N, int K) {
    __shared__ float As[64][17];
    __shared__ float Ws[64][17];
    const int t = threadIdx.x;
    const int tx = t & 15, ty = t >> 4;
    const int row0 = blockIdx.y * 64, col0 = blockIdx.x * 64;
    float acc[4][4] = {};
    const int nk = (K + 15) >> 4;
    for (int kt = 0; kt < nk; ++kt) {
        int k0 = kt * 16;
        #pragma unroll
        for (int e = t; e < 64 * 16; e += 256) {
            int r = e >> 4, c = e & 15;
            int gk = k0 + c;
            int gm = row0 + r;
            As[r][c] = (gm < M && gk < K) ? A[(size_t)gm * K + gk] : 0.f;
            int gn = col0 + r;
            Ws[r][c] = (gn < N && gk < K) ? W[(size_t)gn * K + gk] : 0.f;
        }
        __syncthreads();
        #pragma unroll
        for (int kk = 0; kk < 16; ++kk) {
            float a[4], w[4];
            #pragma unroll
            for (int i = 0; i < 4; ++i) a[i] = As[ty + 16 * i][kk];
            #pragma unroll
            for (int j = 0; j < 4; ++j) w[j] = Ws[tx + 16 * j][kk];
            #pragma unroll
            for (int i = 0; i < 4; ++i)
                #pragma unroll
                for (int j = 0; j < 4; ++j) acc[i][j] += a[i] * w[j];
        }
        __syncthreads();
    }
    #pragma unroll
    for (int i = 0; i < 4; ++i) {
        int m = row0 + ty + 16 * i;
        if (m >= M) continue;
        #pragma unroll
        for (int j = 0; j < 4; ++j) {
            int n = col0 + tx + 16 * j;
            if (n >= N) continue;
            float v = acc[i][j];
            if (MODE == 0) {
                v += bias[n];
            } else if (MODE == 1) {
                v += (n < Dz) ? bias[n] : ((n >= 2 * Dz) ? bias2[n - 2 * Dz] : 0.f);
            } else if (MODE == 2) {
                v += bias[n] + res[(size_t)m * N + n];
            } else {  // gelu exact
                v += bias[n];
                v = 0.5f * v * (1.f + erff(v * 0.70710678118654752f));
            }
            out[(size_t)m * N + n] = v;
        }
    }
}

// ---------------- attention (per b,h block; flash per-thread row) ----------------
__global__ void attn_k(const float* __restrict__ qkv, const float* __restrict__ rpb,
                       float* __restrict__ o) {
    int b = blockIdx.x / Hz, h = blockIdx.x % Hz;
    __shared__ float Kl[Sz * HDz];
    __shared__ float Vl[Sz * HDz];
    __shared__ float Bb[NRDz];
    const float* base = qkv + (size_t)b * Sz * (3 * Dz);
    int t = threadIdx.x;
    for (int idx = t; idx < Sz * HDz; idx += 256) {
        int s = idx / HDz, d = idx % HDz;
        Kl[idx] = base[(size_t)s * (3 * Dz) + Dz + h * HDz + d];
        Vl[idx] = base[(size_t)s * (3 * Dz) + 2 * Dz + h * HDz + d];
    }
    for (int idx = t; idx < NRDz; idx += 256) Bb[idx] = rpb[idx * Hz + h];
    __syncthreads();
    if (t >= Sz) return;
    float q[HDz];
    const float* qp = base + (size_t)t * (3 * Dz) + h * HDz;
    #pragma unroll
    for (int d = 0; d < HDz; ++d) q[d] = qp[d] * SCALEq;
    float m = -1e30f, l = 0.f;
    float acc[HDz];
    #pragma unroll
    for (int d = 0; d < HDz; ++d) acc[d] = 0.f;
    for (int j = 0; j < Sz; ++j) {
        float s;
        if (t == 0)      s = (j == 0) ? Bb[NRDz - 1] : Bb[NRDz - 3];
        else if (j == 0) s = Bb[NRDz - 2];
        else             s = Bb[t - j + (Nz - 1)];
        const float* kr = Kl + j * HDz;
        #pragma unroll
        for (int d = 0; d < HDz; ++d) s += q[d] * kr[d];
        float mn = fmaxf(m, s);
        float scale = __expf(m - mn);
        float p = __expf(s - mn);
        l = l * scale + p;
        const float* vr = Vl + j * HDz;
        #pragma unroll
        for (int d = 0; d < HDz; ++d) acc[d] = acc[d] * scale + p * vr[d];
        m = mn;
    }
    float inv = 1.f / l;
    float* op = o + ((size_t)b * Sz + t) * Dz + h * HDz;
    #pragma unroll
    for (int d = 0; d < HDz; ++d) op[d] = acc[d] * inv;
}

// ---------------- pool (mean over patch tokens) + fc_norm ----------------
__global__ void pool_norm_k(const float* __restrict__ tok, const float* __restrict__ sc,
                            const float* __restrict__ bi, float* __restrict__ pooled) {
    int b = blockIdx.x;
    int t = threadIdx.x;
    float val = 0.f;
    if (t < Dz) {
        const float* base = tok + ((size_t)b * Sz + 1) * Dz + t;
        float s = 0.f;
        for (int si = 0; si < Nz; ++si) s += base[(size_t)si * Dz];
        val = s * (1.f / Nz);
    }
    __shared__ float red[8];
    float sum = val, sq = val * val;
    #pragma unroll
    for (int off = 32; off; off >>= 1) { sum += __shfl_xor(sum, off); sq += __shfl_xor(sq, off); }
    int wave = t >> 6, lane = t & 63;
    if (lane == 0) { red[wave] = sum; red[4 + wave] = sq; }
    __syncthreads();
    sum = red[0] + red[1] + red[2] + red[3];
    sq = red[4] + red[5] + red[6] + red[7];
    float mean = sum * (1.f / Dz);
    float var = sq * (1.f / Dz) - mean * mean;
    float rstd = rsqrtf(var + 1e-6f);
    if (t < Dz) pooled[(size_t)b * Dz + t] = (val - mean) * rstd * sc[t] + bi[t];
}

extern "C" void kernel_launch(void* const* d_in, const int* in_sizes, int n_in,
                              void* d_out, int out_size, void* d_ws, size_t ws_size,
                              hipStream_t stream) {
    const float* x        = (const float*)d_in[0];
    const float* conv_w   = (const float*)d_in[1];
    const float* conv_b   = (const float*)d_in[2];
    const float* cls_tok  = (const float*)d_in[3];
    const float* pos_emb  = (const float*)d_in[4];
    const float* ln1_s    = (const float*)d_in[5];
    const float* ln1_b    = (const float*)d_in[6];
    const float* qkv_w    = (const float*)d_in[7];
    const float* q_bias   = (const float*)d_in[8];
    const float* v_bias   = (const float*)d_in[9];
    const float* rpb      = (const float*)d_in[10];
    const float* proj_w   = (const float*)d_in[11];
    const float* proj_b   = (const float*)d_in[12];
    const float* ln2_s    = (const float*)d_in[13];
    const float* ln2_b    = (const float*)d_in[14];
    const float* fc1_w    = (const float*)d_in[15];
    const float* fc1_b    = (const float*)d_in[16];
    const float* fc2_w    = (const float*)d_in[17];
    const float* fc2_b    = (const float*)d_in[18];
    const float* fcn_s    = (const float*)d_in[19];
    const float* fcn_b    = (const float*)d_in[20];
    const float* head_w   = (const float*)d_in[21];
    const float* head_b   = (const float*)d_in[22];
    float* out = (float*)d_out;

    float* ws = (float*)d_ws;
    float* tok    = ws;                                   // BS*D
    float* hbuf   = tok + (size_t)BS * Dz;                // BS*D (LN out / attn out)
    float* bigbuf = hbuf + (size_t)BS * Dz;               // BS*800 (qkv / mlp mid)
    float* pooled = bigbuf + (size_t)BS * FFz;            // B*D

    // patch embed
    patch_embed_k<<<BS, 256, 0, stream>>>(x, conv_w, conv_b, cls_tok, pos_emb, tok);

    dim3 blk(256);
    for (int l = 0; l < Lz; ++l) {
        // ln1
        ln_k<<<(BS + 3) / 4, blk, 0, stream>>>(tok, hbuf, ln1_s + l * Dz, ln1_b + l * Dz, BS);
        // qkv = h @ qkv_w^T + [q_bias,0,v_bias]
        gemm_nt_k<1><<<dim3((3 * Dz + 63) / 64, (BS + 63) / 64), blk, 0, stream>>>(
            hbuf, qkv_w + (size_t)l * 3 * Dz * Dz, q_bias + l * Dz, v_bias + l * Dz,
            nullptr, bigbuf, BS, 3 * Dz, Dz);
        // attention -> hbuf
        attn_k<<<Bz * Hz, blk, 0, stream>>>(bigbuf, rpb + (size_t)l * NRDz * Hz, hbuf);
        // tok += o @ proj_w^T + proj_b
        gemm_nt_k<2><<<dim3((Dz + 63) / 64, (BS + 63) / 64), blk, 0, stream>>>(
            hbuf, proj_w + (size_t)l * Dz * Dz, proj_b + l * Dz, nullptr,
            tok, tok, BS, Dz, Dz);
        // ln2
        ln_k<<<(BS + 3) / 4, blk, 0, stream>>>(tok, hbuf, ln2_s + l * Dz, ln2_b + l * Dz, BS);
        // mid = gelu(h2 @ fc1_w^T + fc1_b)
        gemm_nt_k<3><<<dim3((FFz + 63) / 64, (BS + 63) / 64), blk, 0, stream>>>(
            hbuf, fc1_w + (size_t)l * FFz * Dz, fc1_b + l * FFz, nullptr,
            nullptr, bigbuf, BS, FFz, Dz);
        // tok += mid @ fc2_w^T + fc2_b
        gemm_nt_k<2><<<dim3((Dz + 63) / 64, (BS + 63) / 64), blk, 0, stream>>>(
            bigbuf, fc2_w + (size_t)l * Dz * FFz, fc2_b + l * Dz, nullptr,
            tok, tok, BS, Dz, FFz);
    }

    // pool + fc_norm
    pool_norm_k<<<Bz, blk, 0, stream>>>(tok, fcn_s, fcn_b, pooled);
    // head
    gemm_nt_k<0><<<dim3((NCz + 63) / 64, (Bz + 63) / 64), blk, 0, stream>>>(
        pooled, head_w, head_b, nullptr, nullptr, out, Bz, NCz, Dz);
}

// Round 2
// 3012.662 us; speedup vs baseline: 2.3472x; 2.3472x over previous
//
#include <hip/hip_runtime.h>
#include <math.h>

#define Bz 64
#define Tz 12000
#define Pz 50
#define Dz 200
#define Lz 12
#define Hz 10
#define HDz 20
#define FFz 800
#define Nz 240
#define Sz 241
#define NRDz 482
#define NCz 1000
#define BS (Bz * Sz)          // 15424
#define SCALEq 0.22360679774997896f

typedef __attribute__((ext_vector_type(8))) short bf16x8;
typedef __attribute__((ext_vector_type(4))) float f32x4;

static __device__ __forceinline__ short f2b(float f) {
    unsigned u = __float_as_uint(f);
    unsigned r = (u + 0x7fffu + ((u >> 16) & 1u)) >> 16;
    return (short)r;
}

// ---------------- f32 -> bf16 convert ----------------
__global__ void f2b_k(const float* __restrict__ in, short* __restrict__ out, int n) {
    int i = blockIdx.x * 256 + threadIdx.x;
    if (i < n) out[i] = f2b(in[i]);
}

// ---------------- patch embed: tok[b,s,d] (f32) ----------------
__global__ void patch_embed_k(const float* __restrict__ x, const float* __restrict__ cw,
                              const float* __restrict__ cb, const float* __restrict__ cls,
                              const float* __restrict__ pos, float* __restrict__ tok) {
    int bs = blockIdx.x;
    int b = bs / Sz, s = bs % Sz;
    int d = threadIdx.x;
    __shared__ float xp[Pz];
    if (s == 0) {
        if (d < Dz) tok[(size_t)bs * Dz + d] = cls[d] + pos[d];
        return;
    }
    if (d < Pz) xp[d] = x[(size_t)b * Tz + (s - 1) * Pz + d];
    __syncthreads();
    if (d < Dz) {
        float acc = cb[d];
        const float* w = cw + d * Pz;
        #pragma unroll
        for (int p = 0; p < Pz; ++p) acc += xp[p] * w[p];
        tok[(size_t)bs * Dz + d] = acc + pos[s * Dz + d];
    }
}

// ---------------- layernorm: f32 in -> bf16 out ----------------
__global__ void ln_k(const float* __restrict__ in, short* __restrict__ out,
                     const float* __restrict__ sc, const float* __restrict__ bi, int rows) {
    int wave = threadIdx.x >> 6, lane = threadIdx.x & 63;
    int row = blockIdx.x * 4 + wave;
    if (row >= rows) return;
    const float* x = in + (size_t)row * Dz;
    float v[4];
    float sum = 0.f;
    #pragma unroll
    for (int i = 0; i < 4; ++i) {
        int d = lane + 64 * i;
        v[i] = (d < Dz) ? x[d] : 0.f;
        sum += v[i];
    }
    #pragma unroll
    for (int off = 32; off; off >>= 1) sum += __shfl_xor(sum, off);
    float mean = sum * (1.f / Dz);
    float var = 0.f;
    #pragma unroll
    for (int i = 0; i < 4; ++i) {
        int d = lane + 64 * i;
        if (d < Dz) { float t = v[i] - mean; var += t * t; }
    }
    #pragma unroll
    for (int off = 32; off; off >>= 1) var += __shfl_xor(var, off);
    var *= (1.f / Dz);
    float rstd = rsqrtf(var + 1e-6f);
    short* o = out + (size_t)row * Dz;
    #pragma unroll
    for (int i = 0; i < 4; ++i) {
        int d = lane + 64 * i;
        if (d < Dz) o[d] = f2b((v[i] - mean) * rstd * sc[d] + bi[d]);
    }
}

// ---------------- MFMA GEMM: out[M,N] = A[M,K](bf16) @ W[N,K](bf16)^T + epilogue ----------------
// MODE 0: f32 out = acc + bias                   (head)
// MODE 1: f32 out = acc + (q_bias|0|v_bias)      (qkv)
// MODE 2: f32 out = acc + bias + res             (proj/fc2 residual)
// MODE 3: bf16 out = gelu(acc + bias)            (fc1)
#define BMt 128
#define BNt 64
#define LDT 40
template <int MODE>
__global__ __launch_bounds__(256) void mfma_gemm_k(
        const short* __restrict__ A, const short* __restrict__ W,
        const float* __restrict__ bias, const float* __restrict__ bias2,
        const float* __restrict__ res, void* __restrict__ outv,
        int M, int N, int K) {
    __shared__ short As[BMt * LDT];
    __shared__ short Ws[BNt * LDT];
    const int t = threadIdx.x;
    const int lane = t & 63, wid = t >> 6;
    const int wm = wid & 1, wn = wid >> 1;      // 2x2 wave grid
    const int row0 = blockIdx.y * BMt, col0 = blockIdx.x * BNt;
    const int l15 = lane & 15, l4 = lane >> 4;

    f32x4 acc[4][2];
    #pragma unroll
    for (int mi = 0; mi < 4; ++mi)
        #pragma unroll
        for (int nj = 0; nj < 2; ++nj) {
            f32x4 z = {0.f, 0.f, 0.f, 0.f};
            acc[mi][nj] = z;
        }

    const int nk = (K + 31) >> 5;
    for (int kt = 0; kt < nk; ++kt) {
        int k0 = kt * 32;
        // stage A: 128 rows x 4 chunks(8 bf16)
        #pragma unroll
        for (int i = 0; i < 2; ++i) {
            int e = t + i * 256;
            int r = e >> 2, c = e & 3;
            int gm = row0 + r, gk = k0 + c * 8;
            bf16x8 v = {0, 0, 0, 0, 0, 0, 0, 0};
            if (gm < M && gk + 8 <= K) v = *(const bf16x8*)(A + (size_t)gm * K + gk);
            *(bf16x8*)(As + r * LDT + c * 8) = v;
        }
        // stage W: 64 rows x 4 chunks
        {
            int r = t >> 2, c = t & 3;
            int gn = col0 + r, gk = k0 + c * 8;
            bf16x8 v = {0, 0, 0, 0, 0, 0, 0, 0};
            if (gn < N && gk + 8 <= K) v = *(const bf16x8*)(W + (size_t)gn * K + gk);
            *(bf16x8*)(Ws + r * LDT + c * 8) = v;
        }
        __syncthreads();
        bf16x8 bfrag[2];
        #pragma unroll
        for (int nj = 0; nj < 2; ++nj)
            bfrag[nj] = *(const bf16x8*)(Ws + (wn * 32 + nj * 16 + l15) * LDT + l4 * 8);
        #pragma unroll
        for (int mi = 0; mi < 4; ++mi) {
            bf16x8 afrag = *(const bf16x8*)(As + (wm * 64 + mi * 16 + l15) * LDT + l4 * 8);
            #pragma unroll
            for (int nj = 0; nj < 2; ++nj)
                acc[mi][nj] = __builtin_amdgcn_mfma_f32_16x16x32_bf16(afrag, bfrag[nj], acc[mi][nj], 0, 0, 0);
        }
        __syncthreads();
    }

    // epilogue: C/D map col=lane&15, row=(lane>>4)*4+reg  [m89]
    #pragma unroll
    for (int mi = 0; mi < 4; ++mi) {
        #pragma unroll
        for (int nj = 0; nj < 2; ++nj) {
            #pragma unroll
            for (int r = 0; r < 4; ++r) {
                int m = row0 + wm * 64 + mi * 16 + l4 * 4 + r;
                int n = col0 + wn * 32 + nj * 16 + l15;
                if (m >= M || n >= N) continue;
                float v = acc[mi][nj][r];
                size_t off = (size_t)m * N + n;
                if (MODE == 0) {
                    ((float*)outv)[off] = v + bias[n];
                } else if (MODE == 1) {
                    v += (n < Dz) ? bias[n] : ((n >= 2 * Dz) ? bias2[n - 2 * Dz] : 0.f);
                    ((float*)outv)[off] = v;
                } else if (MODE == 2) {
                    ((float*)outv)[off] = v + bias[n] + res[off];
                } else {
                    v += bias[n];
                    v = 0.5f * v * (1.f + erff(v * 0.70710678118654752f));
                    ((short*)outv)[off] = f2b(v);
                }
            }
        }
    }
}

// ---------------- attention: qkv f32 in -> bf16 out ----------------
__global__ void attn_k(const float* __restrict__ qkv, const float* __restrict__ rpb,
                       short* __restrict__ o) {
    int b = blockIdx.x / Hz, h = blockIdx.x % Hz;
    __shared__ float Kl[Sz * HDz];
    __shared__ float Vl[Sz * HDz];
    __shared__ float Bb[NRDz];
    const float* base = qkv + (size_t)b * Sz * (3 * Dz);
    int t = threadIdx.x;
    for (int idx = t; idx < Sz * HDz; idx += 256) {
        int s = idx / HDz, d = idx % HDz;
        Kl[idx] = base[(size_t)s * (3 * Dz) + Dz + h * HDz + d];
        Vl[idx] = base[(size_t)s * (3 * Dz) + 2 * Dz + h * HDz + d];
    }
    for (int idx = t; idx < NRDz; idx += 256) Bb[idx] = rpb[idx * Hz + h];
    __syncthreads();
    if (t >= Sz) return;
    float q[HDz];
    const float* qp = base + (size_t)t * (3 * Dz) + h * HDz;
    #pragma unroll
    for (int d = 0; d < HDz; ++d) q[d] = qp[d] * SCALEq;
    float m = -1e30f, l = 0.f;
    float acc[HDz];
    #pragma unroll
    for (int d = 0; d < HDz; ++d) acc[d] = 0.f;
    for (int j = 0; j < Sz; ++j) {
        float s;
        if (t == 0)      s = (j == 0) ? Bb[NRDz - 1] : Bb[NRDz - 3];
        else if (j == 0) s = Bb[NRDz - 2];
        else             s = Bb[t - j + (Nz - 1)];
        const float* kr = Kl + j * HDz;
        #pragma unroll
        for (int d = 0; d < HDz; ++d) s += q[d] * kr[d];
        float mn = fmaxf(m, s);
        float scale = __expf(m - mn);
        float p = __expf(s - mn);
        l = l * scale + p;
        const float* vr = Vl + j * HDz;
        #pragma unroll
        for (int d = 0; d < HDz; ++d) acc[d] = acc[d] * scale + p * vr[d];
        m = mn;
    }
    float inv = 1.f / l;
    short* op = o + ((size_t)b * Sz + t) * Dz + h * HDz;
    #pragma unroll
    for (int d = 0; d < HDz; ++d) op[d] = f2b(acc[d] * inv);
}

// ---------------- pool + fc_norm -> bf16 pooled ----------------
__global__ void pool_norm_k(const float* __restrict__ tok, const float* __restrict__ sc,
                            const float* __restrict__ bi, short* __restrict__ pooled) {
    int b = blockIdx.x;
    int t = threadIdx.x;
    float val = 0.f;
    if (t < Dz) {
        const float* base = tok + ((size_t)b * Sz + 1) * Dz + t;
        float s = 0.f;
        for (int si = 0; si < Nz; ++si) s += base[(size_t)si * Dz];
        val = s * (1.f / Nz);
    }
    __shared__ float red[8];
    float sum = val, sq = val * val;
    #pragma unroll
    for (int off = 32; off; off >>= 1) { sum += __shfl_xor(sum, off); sq += __shfl_xor(sq, off); }
    int wave = t >> 6, lane = t & 63;
    if (lane == 0) { red[wave] = sum; red[4 + wave] = sq; }
    __syncthreads();
    sum = red[0] + red[1] + red[2] + red[3];
    sq = red[4] + red[5] + red[6] + red[7];
    float mean = sum * (1.f / Dz);
    float var = sq * (1.f / Dz) - mean * mean;
    float rstd = rsqrtf(var + 1e-6f);
    if (t < Dz) pooled[(size_t)b * Dz + t] = f2b((val - mean) * rstd * sc[t] + bi[t]);
}

extern "C" void kernel_launch(void* const* d_in, const int* in_sizes, int n_in,
                              void* d_out, int out_size, void* d_ws, size_t ws_size,
                              hipStream_t stream) {
    const float* x        = (const float*)d_in[0];
    const float* conv_w   = (const float*)d_in[1];
    const float* conv_b   = (const float*)d_in[2];
    const float* cls_tok  = (const float*)d_in[3];
    const float* pos_emb  = (const float*)d_in[4];
    const float* ln1_s    = (const float*)d_in[5];
    const float* ln1_b    = (const float*)d_in[6];
    const float* qkv_w    = (const float*)d_in[7];
    const float* q_bias   = (const float*)d_in[8];
    const float* v_bias   = (const float*)d_in[9];
    const float* rpb      = (const float*)d_in[10];
    const float* proj_w   = (const float*)d_in[11];
    const float* proj_b   = (const float*)d_in[12];
    const float* ln2_s    = (const float*)d_in[13];
    const float* ln2_b    = (const float*)d_in[14];
    const float* fc1_w    = (const float*)d_in[15];
    const float* fc1_b    = (const float*)d_in[16];
    const float* fc2_w    = (const float*)d_in[17];
    const float* fc2_b    = (const float*)d_in[18];
    const float* fcn_s    = (const float*)d_in[19];
    const float* fcn_b    = (const float*)d_in[20];
    const float* head_w   = (const float*)d_in[21];
    const float* head_b   = (const float*)d_in[22];
    float* out = (float*)d_out;

    // workspace layout (all 16B aligned)
    char* ws = (char*)d_ws;
    float* tok    = (float*)ws;                               ws += (size_t)BS * Dz * 4;
    short* xln    = (short*)ws;                               ws += (size_t)BS * Dz * 2;
    float* qkvbuf = (float*)ws;                               // BS*600 f32
    short* mid    = (short*)ws;                               // alias: BS*800 bf16 (smaller)
    ws += (size_t)BS * 3 * Dz * 4;
    short* wq = (short*)ws;   ws += (size_t)Lz * 3 * Dz * Dz * 2;
    short* wp = (short*)ws;   ws += (size_t)Lz * Dz * Dz * 2;
    short* w1 = (short*)ws;   ws += (size_t)Lz * FFz * Dz * 2;
    short* w2 = (short*)ws;   ws += (size_t)Lz * Dz * FFz * 2;
    short* wh = (short*)ws;   ws += (size_t)NCz * Dz * 2;
    short* pooledb = (short*)ws;

    // weight conversions (once per call; deterministic)
    {
        int n;
        n = Lz * 3 * Dz * Dz; f2b_k<<<(n + 255) / 256, 256, 0, stream>>>(qkv_w, wq, n);
        n = Lz * Dz * Dz;     f2b_k<<<(n + 255) / 256, 256, 0, stream>>>(proj_w, wp, n);
        n = Lz * FFz * Dz;    f2b_k<<<(n + 255) / 256, 256, 0, stream>>>(fc1_w, w1, n);
        n = Lz * Dz * FFz;    f2b_k<<<(n + 255) / 256, 256, 0, stream>>>(fc2_w, w2, n);
        n = NCz * Dz;         f2b_k<<<(n + 255) / 256, 256, 0, stream>>>(head_w, wh, n);
    }

    patch_embed_k<<<BS, 256, 0, stream>>>(x, conv_w, conv_b, cls_tok, pos_emb, tok);

    dim3 blk(256);
    const int MT = (BS + BMt - 1) / BMt;   // 121
    for (int l = 0; l < Lz; ++l) {
        ln_k<<<(BS + 3) / 4, blk, 0, stream>>>(tok, xln, ln1_s + l * Dz, ln1_b + l * Dz, BS);
        mfma_gemm_k<1><<<dim3((3 * Dz + BNt - 1) / BNt, MT), blk, 0, stream>>>(
            xln, wq + (size_t)l * 3 * Dz * Dz, q_bias + l * Dz, v_bias + l * Dz,
            nullptr, qkvbuf, BS, 3 * Dz, Dz);
        attn_k<<<Bz * Hz, blk, 0, stream>>>(qkvbuf, rpb + (size_t)l * NRDz * Hz, xln);
        mfma_gemm_k<2><<<dim3((Dz + BNt - 1) / BNt, MT), blk, 0, stream>>>(
            xln, wp + (size_t)l * Dz * Dz, proj_b + l * Dz, nullptr,
            tok, tok, BS, Dz, Dz);
        ln_k<<<(BS + 3) / 4, blk, 0, stream>>>(tok, xln, ln2_s + l * Dz, ln2_b + l * Dz, BS);
        mfma_gemm_k<3><<<dim3((FFz + BNt - 1) / BNt, MT), blk, 0, stream>>>(
            xln, w1 + (size_t)l * FFz * Dz, fc1_b + l * FFz, nullptr,
            nullptr, mid, BS, FFz, Dz);
        mfma_gemm_k<2><<<dim3((Dz + BNt - 1) / BNt, MT), blk, 0, stream>>>(
            mid, w2 + (size_t)l * Dz * FFz, fc2_b + l * Dz, nullptr,
            tok, tok, BS, Dz, FFz);
    }

    pool_norm_k<<<Bz, blk, 0, stream>>>(tok, fcn_s, fcn_b, pooledb);
    mfma_gemm_k<0><<<dim3((NCz + BNt - 1) / BNt, 1), blk, 0, stream>>>(
        pooledb, wh, head_b, nullptr, nullptr, out, Bz, NCz, Dz);
}